// Round 5
// baseline (155.875 us; speedup 1.0000x reference)
//
#include <hip/hip_runtime.h>
#include <stdint.h>

#define B_  4
#define T_  4096
#define D_  1024
#define HD_ 64
#define BT_ 16384   // B_*T_

typedef short bf16x8 __attribute__((ext_vector_type(8)));
typedef float f32x4  __attribute__((ext_vector_type(4)));
typedef float f32x16 __attribute__((ext_vector_type(16)));
typedef unsigned short u16;
typedef u16 u16x4 __attribute__((ext_vector_type(4)));
typedef unsigned int u32;
typedef u32 u32x4 __attribute__((ext_vector_type(4)));

#define M0L2_  11.54156032f  // M0(=8) * log2(e)
#define QSCALE_ 0.18033688f  // 0.125 * log2(e): folds softmax scale AND exp2 base

#define CPB_   264           // chunks (=attn blocks) per batch, 4 tile-tasks each
#define NSLOT_ (4 * CPB_ * 2)

__device__ __forceinline__ u16 f2bf(float f) {
    union { float f; unsigned u; } v; v.f = f;
    unsigned r = (v.u + 0x7FFF + ((v.u >> 16) & 1)) >> 16;
    return (u16)r;
}
__device__ __forceinline__ float bf2f(u16 u) {
    union { unsigned u; float f; } v; v.u = ((unsigned)u) << 16;
    return v.f;
}
// packed f32x2 -> bf16x2 (lo = first operand)
__device__ __forceinline__ u32 cvt_pk_bf16(float lo, float hi) {
    u32 r;
    asm("v_cvt_pk_bf16_f32 %0, %1, %2" : "=v"(r) : "v"(lo), "v"(hi));
    return r;
}

// ---------------------------------------------------------------------------
// Kernel 0: W fp32 -> bf16 in MFMA-FRAGMENT order.
// Fragment f = (kc*12 + colg)*2 + ks  (kc 0..15, colg 0..11 col-group of 16,
// ks 0..1). Within a frag: lane = quad*16 + l16, 8 bf16 per lane.
// Element (lane, j) = W[colg*16 + l16][kc*64 + ks*32 + quad*8 + j].
// => qkv's B-frag load is ONE coalesced 1 KB global_load per (g,ks).
// ---------------------------------------------------------------------------
__global__ __launch_bounds__(256) void wconv_kernel(
    const float* __restrict__ wq, const float* __restrict__ wk,
    const float* __restrict__ wv, u16* __restrict__ wb)
{
    const int cid  = blockIdx.x * 256 + threadIdx.x;   // 96 blocks -> 24576 chunks
    const int n    = cid >> 7;          // 0..191 output col (W row)
    const int koct = cid & 127;         // k-octet 0..127
    const int mat  = n >> 6;
    const int row  = n & 63;
    const float* src = (mat == 0) ? wq : ((mat == 1) ? wk : wv);
    const float* p = src + row * 1024 + koct * 8;
    f32x4 a0 = *(const f32x4*)p;
    f32x4 a1 = *(const f32x4*)(p + 4);
    u32x4 b;
    b[0] = cvt_pk_bf16(a0[0], a0[1]);
    b[1] = cvt_pk_bf16(a0[2], a0[3]);
    b[2] = cvt_pk_bf16(a1[0], a1[1]);
    b[3] = cvt_pk_bf16(a1[2], a1[3]);
    const int kc  = koct >> 3, ksl = (koct >> 2) & 1, qd = koct & 3;
    const int f   = (kc * 12 + (n >> 4)) * 2 + ksl;
    *(u32x4*)(wb + (size_t)(f * 64 + qd * 16 + (n & 15)) * 8) = b;
}

// ---------------------------------------------------------------------------
// Kernel 1: QKV projection — ZERO LDS, ZERO barriers.
// W B-frags stream from L2 in fragment order (1 KB coalesced loads); x
// A-frags read per-lane from global fp32 (16 full cache lines per load,
// 100% line use) and packed in-register via cvt_pk. One-kc-ahead register
// prefetch; each wave fully independent.
// Emits: qs[row][h] (x 0.125*log2e), kss[row][h], vssT[h][row].
// ---------------------------------------------------------------------------
__global__ __launch_bounds__(256) void qkv_kernel(
    const float* __restrict__ x, const u16* __restrict__ wb,
    u16* __restrict__ qs, u16* __restrict__ kss, u16* __restrict__ vssT)
{
    const int tid  = threadIdx.x;
    const int lane = tid & 63;
    const int w    = tid >> 6;
    const int quad = lane >> 4;
    const int l16  = lane & 15;
    const int row0 = blockIdx.x * 32;
    const int sp   = w >> 1;            // stripe (16 rows)
    const int gh   = (w & 1) * 6;       // g-group offset

    f32x4 acc[6];
    #pragma unroll
    for (int g = 0; g < 6; ++g) acc[g] = (f32x4)0.0f;

    const float* xq = x + (size_t)(row0 + sp * 16 + l16) * D_ + quad * 8;
    const u16*   wp = wb + (size_t)lane * 8;

    f32x4 xr[4]; bf16x8 wc[12];
    #pragma unroll
    for (int ks = 0; ks < 2; ++ks) {
        xr[ks * 2]     = *(const f32x4*)(xq + ks * 32);
        xr[ks * 2 + 1] = *(const f32x4*)(xq + ks * 32 + 4);
    }
    #pragma unroll
    for (int g = 0; g < 6; ++g)
        #pragma unroll
        for (int ks = 0; ks < 2; ++ks)
            wc[g * 2 + ks] = *(const bf16x8*)(wp + (size_t)((gh + g) * 2 + ks) * 512);

    for (int kc = 0; kc < 16; ++kc) {
        f32x4 xn[4]; bf16x8 wn[12];
        if (kc < 15) {
            const float* xq1 = xq + (kc + 1) * 64;
            #pragma unroll
            for (int ks = 0; ks < 2; ++ks) {
                xn[ks * 2]     = *(const f32x4*)(xq1 + ks * 32);
                xn[ks * 2 + 1] = *(const f32x4*)(xq1 + ks * 32 + 4);
            }
            #pragma unroll
            for (int g = 0; g < 6; ++g)
                #pragma unroll
                for (int ks = 0; ks < 2; ++ks)
                    wn[g * 2 + ks] = *(const bf16x8*)(wp + (size_t)((kc + 1) * 24 + (gh + g) * 2 + ks) * 512);
        }
        bf16x8 a[2];
        #pragma unroll
        for (int ks = 0; ks < 2; ++ks) {
            u32x4 px;
            px[0] = cvt_pk_bf16(xr[ks * 2][0], xr[ks * 2][1]);
            px[1] = cvt_pk_bf16(xr[ks * 2][2], xr[ks * 2][3]);
            px[2] = cvt_pk_bf16(xr[ks * 2 + 1][0], xr[ks * 2 + 1][1]);
            px[3] = cvt_pk_bf16(xr[ks * 2 + 1][2], xr[ks * 2 + 1][3]);
            a[ks] = __builtin_bit_cast(bf16x8, px);
        }
        #pragma unroll
        for (int ks = 0; ks < 2; ++ks)
            #pragma unroll
            for (int g = 0; g < 6; ++g)
                acc[g] = __builtin_amdgcn_mfma_f32_16x16x32_bf16(a[ks], wc[g * 2 + ks], acc[g], 0, 0, 0);
        if (kc < 15) {
            #pragma unroll
            for (int i = 0; i < 4; ++i)  xr[i] = xn[i];
            #pragma unroll
            for (int i = 0; i < 12; ++i) wc[i] = wn[i];
        }
    }
    // epilogue: C/D layout row=quad*4+r, col=l16
    #pragma unroll
    for (int g = 0; g < 6; ++g) {
        const int n = (gh + g) * 16 + l16;
        const int j = n >> 6, h = n & 63;
        const int rbase = row0 + sp * 16 + quad * 4;
        if (j == 0) {
            #pragma unroll
            for (int r = 0; r < 4; ++r) qs[(size_t)(rbase + r) * HD_ + h] = f2bf(acc[g][r] * QSCALE_);
        } else if (j == 1) {
            #pragma unroll
            for (int r = 0; r < 4; ++r) kss[(size_t)(rbase + r) * HD_ + h] = f2bf(acc[g][r]);
        } else {
            u16x4 v;
            #pragma unroll
            for (int r = 0; r < 4; ++r) v[r] = f2bf(acc[g][r]);
            *(u16x4*)(vssT + (size_t)h * BT_ + rbase) = v;
        }
    }
}

// ---------------------------------------------------------------------------
// Kernel 2: flash attention, 32x32 swapped-QK, P fully in registers.
// (unchanged from round 4 — verified)
// ---------------------------------------------------------------------------
__global__ __launch_bounds__(256, 4) void attn_kernel(
    const u16* __restrict__ qs, const u16* __restrict__ kss,
    const u16* __restrict__ vssT,
    float* __restrict__ pl, u16* __restrict__ pO)
{
    __shared__ __align__(16) u16 kt2[8 * 65 * 8];
    __shared__ __align__(16) u16 vt2[8 * 65 * 8];

    const int m = blockIdx.x % CPB_;
    const int b = blockIdx.x / CPB_;

    int t0, bound, qtA, qtB;
    if (m < 240)      { int u = m >> 4; t0 = (m & 15) * 4; bound = 2 * u + 2; qtA = u;  qtB = 30 - u; }
    else if (m < 248) { t0 = (m - 240) * 4; bound = 1 << 30; qtA = 15; qtB = 15; }
    else              { t0 = (m - 248) * 4; bound = 1 << 30; qtA = 31; qtB = 31; }

    const int tid  = threadIdx.x;
    const int lane = tid & 63;
    const int w    = tid >> 6;
    const int l31  = lane & 31;
    const int hi   = lane >> 5;
    const size_t base = (size_t)b * T_;

    int qt    = (t0 < bound) ? qtA : qtB;
    int kti   = (t0 < bound) ? t0 : (t0 - bound);
    int qrow0 = qt * 128 + w * 32;

    // Q B-frags: lane holds Q[q=l31][ds*16 + hi*8 + 0..7]
    bf16x8 qf[4];
    #pragma unroll
    for (int ds = 0; ds < 4; ++ds)
        qf[ds] = *(const bf16x8*)(qs + (base + qrow0 + l31) * HD_ + ds * 16 + hi * 8);

    f32x16 o0 = (f32x16)0.0f, o1 = (f32x16)0.0f;
    float l_acc = 0.0f;

    // staging: thread t -> row t>>2 (key for K / d for V), 32B at col (t&3)*16
    const int srow = tid >> 2, q4 = tid & 3;
    const u16* kp = kss  + (base + srow) * HD_ + q4 * 16;
    const u16* vp = vssT + (size_t)srow * BT_ + base + q4 * 16;
    u16* kdst = kt2 + ((((srow >> 5) * 4 + q4) * 65 + (srow & 31)) * 8);
    u16* vdst = vt2 + ((((srow >> 5) * 4 + q4) * 65 + (srow & 31)) * 8);

    bf16x8 kr0, kr1, vr0, vr1;
    {
        const u16* k0 = kp + (size_t)kti * 64 * HD_;
        kr0 = *(const bf16x8*)k0; kr1 = *(const bf16x8*)(k0 + 8);
        const u16* v0 = vp + kti * 64;
        vr0 = *(const bf16x8*)v0; vr1 = *(const bf16x8*)(v0 + 8);
    }

    auto FLUSH = [&](int role) {
        const int slot = (b * CPB_ + m) * 2 + role;
        u32 la = __builtin_bit_cast(u32, l_acc), lb = la;
        asm("v_permlane32_swap_b32 %0, %1" : "+v"(la), "+v"(lb));
        float lfull = __builtin_bit_cast(float, la) + __builtin_bit_cast(float, lb);
        if (hi == 0) pl[slot * 128 + w * 32 + l31] = lfull;
        #pragma unroll
        for (int reg = 0; reg < 16; ++reg) {
            int row = w * 32 + (reg & 3) + 8 * (reg >> 2) + 4 * hi;
            pO[(size_t)slot * 8192 + row * 64 + l31]      = f2bf(o0[reg]);
            pO[(size_t)slot * 8192 + row * 64 + 32 + l31] = f2bf(o1[reg]);
        }
    };

    for (int step = 0; step < 4; ++step) {
        const int i = t0 + step;
        __syncthreads();
        *(bf16x8*)(kdst)       = kr0;
        *(bf16x8*)(kdst + 256) = kr1;
        *(bf16x8*)(vdst)       = vr0;
        *(bf16x8*)(vdst + 256) = vr1;
        __syncthreads();

        int kti_next = 0;
        if (step < 3) {
            kti_next = (i + 1 < bound) ? (i + 1) : (i + 1 - bound);
            const u16* k0 = kp + (size_t)kti_next * 64 * HD_;
            kr0 = *(const bf16x8*)k0; kr1 = *(const bf16x8*)(k0 + 8);
            const u16* v0 = vp + kti_next * 64;
            vr0 = *(const bf16x8*)v0; vr1 = *(const bf16x8*)(v0 + 8);
        }

        if (kti * 64 <= qrow0 + 31) {      // warp-uniform skip of fully-masked tiles
            const bool diag = (kti * 64 + 63 > qrow0);
            const int  qa   = qrow0 + l31;
            u32 wv[16];
            #pragma unroll
            for (int kg = 0; kg < 2; ++kg) {
                f32x16 s = (f32x16)0.0f;
                __builtin_amdgcn_s_setprio(1);
                #pragma unroll
                for (int ds = 0; ds < 4; ++ds) {
                    bf16x8 af = *(const bf16x8*)(kt2 + ((kg * 4 + ds) * 65 + lane) * 8);
                    s = __builtin_amdgcn_mfma_f32_32x32x16_bf16(af, qf[ds], s, 0, 0, 0);
                }
                __builtin_amdgcn_s_setprio(0);
                float lp = 0.0f;
                #pragma unroll
                for (int rp = 0; rp < 8; ++rp) {
                    float e0 = __builtin_amdgcn_exp2f(s[2 * rp]     - M0L2_);
                    float e1 = __builtin_amdgcn_exp2f(s[2 * rp + 1] - M0L2_);
                    if (diag) {
                        const int k0e = kti * 64 + kg * 32 + ((2 * rp) & 3) + 8 * ((2 * rp) >> 2) + 4 * hi;
                        if (k0e > qa)     e0 = 0.0f;
                        if (k0e + 1 > qa) e1 = 0.0f;   // reg 2rp+1 = key k0e+1
                    }
                    lp += e0 + e1;
                    wv[kg * 8 + rp] = cvt_pk_bf16(e0, e1);
                }
                l_acc += lp;
            }
            // PA frags: one swap fills two output words (guide §B recipe)
            bf16x8 pa[4];
            #pragma unroll
            for (int ks = 0; ks < 4; ++ks) {
                const int kg2 = ks >> 1, k1 = ks & 1;
                u32 x0 = wv[kg2 * 8 + k1 * 4 + 0], y0 = wv[kg2 * 8 + k1 * 4 + 2];
                u32 x1 = wv[kg2 * 8 + k1 * 4 + 1], y1 = wv[kg2 * 8 + k1 * 4 + 3];
                asm("v_permlane32_swap_b32 %0, %1" : "+v"(x0), "+v"(y0));
                asm("v_permlane32_swap_b32 %0, %1" : "+v"(x1), "+v"(y1));
                u32x4 t; t[0] = x0; t[1] = x1; t[2] = y0; t[3] = y1;
                pa[ks] = __builtin_bit_cast(bf16x8, t);
            }
            __builtin_amdgcn_s_setprio(1);
            #pragma unroll
            for (int ks = 0; ks < 4; ++ks) {
                bf16x8 vf0 = *(const bf16x8*)(vt2 + ((0 * 4 + ks) * 65 + lane) * 8);
                o0 = __builtin_amdgcn_mfma_f32_32x32x16_bf16(pa[ks], vf0, o0, 0, 0, 0);
                bf16x8 vf1 = *(const bf16x8*)(vt2 + ((1 * 4 + ks) * 65 + lane) * 8);
                o1 = __builtin_amdgcn_mfma_f32_32x32x16_bf16(pa[ks], vf1, o1, 0, 0, 0);
            }
            __builtin_amdgcn_s_setprio(0);
        }

        kti = kti_next;
        if (step < 3 && (i + 1) == bound) {   // q-tile crossing: flush + reset
            FLUSH(0);
            o0 = (f32x16)0.0f; o1 = (f32x16)0.0f; l_acc = 0.0f;
            qt = qtB; qrow0 = qt * 128 + w * 32;
            #pragma unroll
            for (int ds = 0; ds < 4; ++ds)
                qf[ds] = *(const bf16x8*)(qs + (base + qrow0 + l31) * HD_ + ds * 16 + hi * 8);
        }
    }
    FLUSH((t0 + 3 >= bound) ? 1 : 0);
}

// ---------------------------------------------------------------------------
// Kernel 3: merge partials. grid = (b, qt2, row-half) = 256 blocks.
// (unchanged from round 4 — verified)
// ---------------------------------------------------------------------------
__global__ __launch_bounds__(256) void merge_kernel(
    const float* __restrict__ pl, const u16* __restrict__ pO,
    float* __restrict__ out)
{
    const int bi  = blockIdx.x;            // b*64 + qt2*2 + rh
    const int rh  = bi & 1;
    const int qt2 = (bi >> 1) & 31;
    const int b   = bi >> 6;

    int c0, c1, role, mbase;
    if (qt2 <= 14)      { int u = qt2;      c0 = 0;                 c1 = (2 * u + 1) >> 2; role = 0; mbase = u * 16; }
    else if (qt2 == 15) { c0 = 0;           c1 = 7;                 role = 0; mbase = 240; }
    else if (qt2 <= 30) { int u = 30 - qt2; c0 = (2 * u + 2) >> 2;  c1 = 15; role = 1; mbase = u * 16; }
    else                { c0 = 0;           c1 = 15;                role = 0; mbase = 248; }

    const int row = rh * 64 + (threadIdx.x >> 2);
    const int hg  = (threadIdx.x & 3) * 16;

    float L = 0.0f;
    float o[16];
    #pragma unroll
    for (int i = 0; i < 16; ++i) o[i] = 0.0f;
    for (int c = c0; c <= c1; ++c) {
        const int slot = (b * CPB_ + mbase + c) * 2 + role;
        L += pl[slot * 128 + row];
        const u16* p = pO + (size_t)slot * 8192 + row * 64 + hg;
        bf16x8 v0 = *(const bf16x8*)p;
        bf16x8 v1 = *(const bf16x8*)(p + 8);
        #pragma unroll
        for (int i = 0; i < 8; ++i) { o[i] += bf2f((u16)v0[i]); o[8 + i] += bf2f((u16)v1[i]); }
    }
    const float inv = 1.0f / L;
    float* op = out + ((size_t)b * T_ + qt2 * 128 + row) * HD_ + hg;
    #pragma unroll
    for (int j = 0; j < 4; ++j) {
        f32x4 v;
        #pragma unroll
        for (int i = 0; i < 4; ++i) v[i] = o[j * 4 + i] * inv;
        *(f32x4*)(op + j * 4) = v;
    }
}

extern "C" void kernel_launch(void* const* d_in, const int* in_sizes, int n_in,
                              void* d_out, int out_size, void* d_ws, size_t ws_size,
                              hipStream_t stream) {
    const float* x  = (const float*)d_in[0];
    const float* wq = (const float*)d_in[1];
    const float* wk = (const float*)d_in[2];
    const float* wv = (const float*)d_in[3];

    const size_t NE = (size_t)BT_ * HD_;           // 1,048,576
    char* ws = (char*)d_ws;
    u16* qs   = (u16*)ws;                          // 2 MB (Q pre-scaled)
    u16* kss  = qs  + NE;                          // 2 MB
    u16* vssT = kss + NE;                          // 2 MB, [h][B*T]
    u16* wb   = vssT + NE;                         // 384 KB bf16 W (fragment order)
    float* pl = (float*)(wb + 192 * 1024);         // NSLOT_*128 f32 = 1.08 MB
    u16* pO   = (u16*)(pl + (size_t)NSLOT_ * 128); // NSLOT_*8192 bf16 = 34.6 MB
    float* out = (float*)d_out;

    wconv_kernel<<<dim3(96),        dim3(256), 0, stream>>>(wq, wk, wv, wb);
    qkv_kernel  <<<dim3(512),       dim3(256), 0, stream>>>(x, wb, qs, kss, vssT);
    attn_kernel <<<dim3(4 * CPB_),  dim3(256), 0, stream>>>(qs, kss, vssT, pl, pO);
    merge_kernel<<<dim3(256),       dim3(256), 0, stream>>>(pl, pO, out);
}